// Round 5
// baseline (130.127 us; speedup 1.0000x reference)
//
#include <hip/hip_runtime.h>

// Fused 2-level inverse Haar DWT (UnPatcher, PATCH_SIZE=4), LDS-staged,
// nontemporal output stores.
// Input  x:   [8, 256, 96, 96]  fp32
// Output out: [8, 16, 384, 384] fp32
//
// Block = 384 threads, tile = (b, g, 4 input rows, 96 q).
//  Phase 1: 1536 float4 chunks (16 ch x 4 rows x 24 q-chunks) loaded flat,
//           4 global_load_dwordx4 per thread -> LDS (conflict-free).
//  Phase 2: thread (r, q) reads 16 scalars from LDS (2 lanes/bank, free),
//           2-level +/-1 butterfly (per-level scale 2*S*S == 1), writes a
//           4x4 output tile as 4 lane-contiguous nontemporal dwordx4 stores
//           (1 KB contiguous per wave per store; write-once stream, so NT
//           keeps L2/L3 free for the harness-warmed input reads).

#define B_   8
#define CIN  256
#define G_   16
#define H_   96
#define W_   96
#define OW   384
#define ROWS 4                     // input rows per block
#define NT_  (ROWS * W_)           // 384 threads
#define NCHUNK (16 * ROWS * (W_ / 4))  // 1536 float4 chunks per tile

typedef float v4f __attribute__((ext_vector_type(4)));  // native vector for NT store

__global__ __launch_bounds__(NT_) void idwt2_lds_nt(const float* __restrict__ x,
                                                    float* __restrict__ out) {
    __shared__ float lds[16 * ROWS * W_];  // 24 KB: [ch_idx][row][q]

    const int tid = threadIdx.x;
    // blockIdx.x = ((b*G_ + g) * (H_/ROWS)) + pblk
    int bid  = blockIdx.x;
    int pblk = bid % (H_ / ROWS);
    int bg   = bid / (H_ / ROWS);      // b*G_ + g
    int g    = bg % G_;
    int b    = bg / G_;
    int p0   = pblk * ROWS;

    const size_t plane = (size_t)H_ * W_;  // 9216
    const float* xb = x + (size_t)b * CIN * plane;

    // ---- Phase 1: global -> LDS ----
#pragma unroll
    for (int it = 0; it < NCHUNK / NT_; ++it) {
        int i      = tid + it * NT_;          // 0..1535
        int ch_idx = i / (ROWS * (W_ / 4));   // /96
        int rem    = i % (ROWS * (W_ / 4));
        int row    = rem / (W_ / 4);          // /24
        int cq     = rem % (W_ / 4);
        int k = ch_idx & 3;
        int m = ch_idx >> 2;
        int channel = g + 16 * k + 64 * m;
        v4f f = *reinterpret_cast<const v4f*>(
            xb + (size_t)channel * plane + (size_t)(p0 + row) * W_ + 4 * cq);
        *reinterpret_cast<v4f*>(&lds[(ch_idx * ROWS + row) * W_ + 4 * cq]) = f;
    }
    __syncthreads();

    // ---- Phase 2: butterfly + store ----
    int r = tid / W_;   // 0..3
    int q = tid % W_;   // 0..95

    float v[4][4];  // v[k][m]
#pragma unroll
    for (int k = 0; k < 4; ++k) {
#pragma unroll
        for (int m = 0; m < 4; ++m) {
            v[k][m] = lds[((k + 4 * m) * ROWS + r) * W_ + q];
        }
    }

    // Level 1 (inner, channel stride 64): t[k][2*dh+dw]
    float t[4][4];
#pragma unroll
    for (int k = 0; k < 4; ++k) {
        float u0 = v[k][0] + v[k][1];
        float u1 = v[k][0] - v[k][1];
        float u2 = v[k][2] + v[k][3];
        float u3 = v[k][2] - v[k][3];
        t[k][0] = u0 + u2;
        t[k][1] = u0 - u2;
        t[k][2] = u1 + u3;
        t[k][3] = u1 - u3;
    }

    // Level 2 (outer, channel stride 16)
    float rowv[4][4];
#pragma unroll
    for (int dh = 0; dh < 2; ++dh) {
#pragma unroll
        for (int dw = 0; dw < 2; ++dw) {
            int i = 2 * dh + dw;
            float a0 = t[0][i] + t[1][i];
            float a1 = t[0][i] - t[1][i];
            float a2 = t[2][i] + t[3][i];
            float a3 = t[2][i] - t[3][i];
            rowv[2 * dh + 0][2 * dw + 0] = a0 + a2;
            rowv[2 * dh + 0][2 * dw + 1] = a0 - a2;
            rowv[2 * dh + 1][2 * dw + 0] = a1 + a3;
            rowv[2 * dh + 1][2 * dw + 1] = a1 - a3;
        }
    }

    float* obase = out + ((size_t)(b * G_ + g) * OW + 4 * (size_t)(p0 + r)) * OW + 4 * (size_t)q;
#pragma unroll
    for (int rr = 0; rr < 4; ++rr) {
        v4f f4 = {rowv[rr][0], rowv[rr][1], rowv[rr][2], rowv[rr][3]};
        __builtin_nontemporal_store(f4, reinterpret_cast<v4f*>(obase + (size_t)rr * OW));
    }
}

extern "C" void kernel_launch(void* const* d_in, const int* in_sizes, int n_in,
                              void* d_out, int out_size, void* d_ws, size_t ws_size,
                              hipStream_t stream) {
    const float* x = (const float*)d_in[0];
    float* out = (float*)d_out;
    const int grid = B_ * G_ * (H_ / ROWS);  // 3072
    idwt2_lds_nt<<<grid, NT_, 0, stream>>>(x, out);
}